// Round 7
// baseline (15286.928 us; speedup 1.0000x reference)
//
#include <hip/hip_runtime.h>
#include <stdint.h>

#define N_SITES 144
#define NHID    256
#define NSAMP   1024
#define MB      4          // samples per block
#define TPB     768        // one gate-column per thread; 12 waves = 3 waves/SIMD
#define NCOL    768

typedef __attribute__((ext_vector_type(16))) uint32_t su16;  // SGPR x16 tuple

__device__ __forceinline__ uint32_t rotl32(uint32_t v, uint32_t r) {
    return (v << r) | (v >> (32u - r));
}

// JAX threefry2x32: 20 rounds, key injections every 4
__device__ __forceinline__ void threefry(uint32_t k0, uint32_t k1,
                                         uint32_t x0, uint32_t x1,
                                         uint32_t& o0, uint32_t& o1) {
    uint32_t ks0 = k0, ks1 = k1, ks2 = k0 ^ k1 ^ 0x1BD11BDAu;
    x0 += ks0; x1 += ks1;
#define RG4(a,b,c,d) \
    x0 += x1; x1 = rotl32(x1,a); x1 ^= x0; \
    x0 += x1; x1 = rotl32(x1,b); x1 ^= x0; \
    x0 += x1; x1 = rotl32(x1,c); x1 ^= x0; \
    x0 += x1; x1 = rotl32(x1,d); x1 ^= x0;
    RG4(13,15,26,6)  x0 += ks1; x1 += ks2 + 1u;
    RG4(17,29,16,24) x0 += ks2; x1 += ks0 + 2u;
    RG4(13,15,26,6)  x0 += ks0; x1 += ks1 + 3u;
    RG4(17,29,16,24) x0 += ks1; x1 += ks2 + 4u;
    RG4(13,15,26,6)  x0 += ks2; x1 += ks0 + 5u;
#undef RG4
    o0 = x0; o1 = x1;
}

__device__ __forceinline__ float gumbel_from_bits(uint32_t bits) {
#pragma clang fp contract(off)
    const float TINY = 1.17549435e-38f;          // finfo(f32).tiny
    uint32_t fb = (bits >> 9) | 0x3f800000u;
    float u = __uint_as_float(fb) - 1.0f;        // [0,1)
    u = u * (1.0f - TINY) + TINY;                // matches JAX uniform()
    u = fmaxf(TINY, u);
    return -logf(-logf(u));
}

// 4 k-steps of the phase-A fmaf chain from an SGPR h-buffer.
// k order ascending, m order 0..3 within k — byte-identical to verified R2.
#define K4(BUF, KB) \
    { \
        float wv0 = rp0[(size_t)((KB) + 0) * NCOL]; \
        float wv1 = rp0[(size_t)((KB) + 1) * NCOL]; \
        float wv2 = rp0[(size_t)((KB) + 2) * NCOL]; \
        float wv3 = rp0[(size_t)((KB) + 3) * NCOL]; \
        a0 = fmaf(__uint_as_float(BUF[0]),  wv0, a0); \
        a1 = fmaf(__uint_as_float(BUF[1]),  wv0, a1); \
        a2 = fmaf(__uint_as_float(BUF[2]),  wv0, a2); \
        a3 = fmaf(__uint_as_float(BUF[3]),  wv0, a3); \
        a0 = fmaf(__uint_as_float(BUF[4]),  wv1, a0); \
        a1 = fmaf(__uint_as_float(BUF[5]),  wv1, a1); \
        a2 = fmaf(__uint_as_float(BUF[6]),  wv1, a2); \
        a3 = fmaf(__uint_as_float(BUF[7]),  wv1, a3); \
        a0 = fmaf(__uint_as_float(BUF[8]),  wv2, a0); \
        a1 = fmaf(__uint_as_float(BUF[9]),  wv2, a1); \
        a2 = fmaf(__uint_as_float(BUF[10]), wv2, a2); \
        a3 = fmaf(__uint_as_float(BUF[11]), wv2, a3); \
        a0 = fmaf(__uint_as_float(BUF[12]), wv3, a0); \
        a1 = fmaf(__uint_as_float(BUF[13]), wv3, a1); \
        a2 = fmaf(__uint_as_float(BUF[14]), wv3, a2); \
        a3 = fmaf(__uint_as_float(BUF[15]), wv3, a3); \
    }

__global__ __launch_bounds__(TPB, 1)
void rnn_sample_kernel(const float* __restrict__ kern,   // [2,768]
                       const float* __restrict__ rec,    // [256,768]
                       const float* __restrict__ bias,   // [2,768]
                       const float* __restrict__ dw,     // [256,2]
                       const float* __restrict__ db,     // [2]
                       float* __restrict__ out,          // samples ++ logP
                       float* __restrict__ hws)          // per-block 2-slot h ring (2048 f)
{
    const int t    = threadIdx.x;          // 0..767 == gate column index
    const int blk  = blockIdx.x;
    const int b0   = blk * MB;
    const int wv   = t >> 6;
    const int lane = t & 63;

    __shared__ float    pacc[MB][NCOL];     // phase-A partials (12 KB)
    __shared__ uint32_t keyA[N_SITES], keyB[N_SITES];
    __shared__ float    wred[4][8];
    __shared__ int      sPrev[MB];
    __shared__ float    lgP[MB];

    float* hbase = hws + (size_t)blk * 2048;   // 2 slots x 1024 floats

    // ---- per-thread constants (threads 0..255 only: gate triples) ----
    float kz0 = 0.f, kr0 = 0.f, kn0 = 0.f, kz1 = 0.f, kr1 = 0.f, kn1 = 0.f;
    float b0z = 0.f, b0r = 0.f, b0n = 0.f, b1z = 0.f, b1r = 0.f, b1n = 0.f;
    float dwa = 0.f, dwb = 0.f, dba = 0.f, dbb = 0.f;
    float4 hold = make_float4(0.f, 0.f, 0.f, 0.f);   // h for unit t (t<256), in regs
    if (t < NHID) {
        const int c0 = t, c1 = t + 256, c2 = t + 512;
        kz0 = kern[c0];       kr0 = kern[c1];       kn0 = kern[c2];
        kz1 = kern[768 + c0]; kr1 = kern[768 + c1]; kn1 = kern[768 + c2];
        b0z = bias[c0];       b0r = bias[c1];       b0n = bias[c2];
        b1z = bias[768 + c0]; b1r = bias[768 + c1]; b1n = bias[768 + c2];
        dwa = dw[2 * t];      dwb = dw[2 * t + 1];
        dba = db[0];          dbb = db[1];
        ((float4*)hbase)[t] = hold;          // slot 0 = h0 = 0
    }
    if (t < MB) { sPrev[t] = -1; lgP[t] = 0.f; }
    if (t < N_SITES) {
        uint32_t o0, o1;
        threefry(0u, 42u, 0u, (uint32_t)t, o0, o1);   // foldlike split: counter = n
        keyA[t] = o0; keyB[t] = o1;
    }
    __syncthreads();   // drains the slot-0 h store to L2

    const float* rp0 = rec + t;

    for (int n = 0; n < N_SITES; ++n) {
        // ---- phase A: h via scalar loads (SGPRs), weights via vector loads.
        //      K$ may hold stale h lines from 2 steps ago -> invalidate, then
        //      refills come from L2 (stores drained at the last barrier). ----
        const uint32_t* hp = (const uint32_t*)(hbase + (n & 1) * 1024);
        float a0 = 0.f, a1 = 0.f, a2 = 0.f, a3 = 0.f;
        su16 hA0, hA1, hB0, hB1;
        asm volatile("s_dcache_inv\n\t"
                     "s_waitcnt lgkmcnt(0)\n\t"
                     "s_load_dwordx16 %0, %2, 0\n\t"
                     "s_load_dwordx16 %1, %2, 64"
                     : "=&s"(hA0), "=&s"(hA1) : "s"(hp));
#pragma unroll
        for (int wp = 0; wp < 16; ++wp) {
            // window 2wp: wait A, prefetch window 2wp+1 into B, compute A
            asm volatile("s_waitcnt lgkmcnt(0)" : "+s"(hA0), "+s"(hA1));
            asm volatile("s_load_dwordx16 %0, %2, %3\n\t"
                         "s_load_dwordx16 %1, %2, %4"
                         : "=&s"(hB0), "=&s"(hB1)
                         : "s"(hp), "i"((2 * wp + 1) * 128), "i"((2 * wp + 1) * 128 + 64));
            K4(hA0, 16 * wp);
            K4(hA1, 16 * wp + 4);
            // window 2wp+1: wait B, prefetch window 2wp+2 into A, compute B
            asm volatile("s_waitcnt lgkmcnt(0)" : "+s"(hB0), "+s"(hB1));
            if (wp < 15) {
                asm volatile("s_load_dwordx16 %0, %2, %3\n\t"
                             "s_load_dwordx16 %1, %2, %4"
                             : "=&s"(hA0), "=&s"(hA1)
                             : "s"(hp), "i"((2 * wp + 2) * 128), "i"((2 * wp + 2) * 128 + 64));
            }
            K4(hB0, 16 * wp + 8);
            K4(hB1, 16 * wp + 12);
        }
        pacc[0][t] = a0; pacc[1][t] = a1; pacc[2][t] = a2; pacc[3][t] = a3;
        __syncthreads();   // B1: pacc + sPrev (from prev step's D) published

        // ---- phases B+C: threads 0..255 (gates, h update, dense partials) ----
        float hnew[MB];
        if (t < NHID) {
            float hold4[MB] = { hold.x, hold.y, hold.z, hold.w };
            {
#pragma clang fp contract(off)
#pragma unroll
                for (int m = 0; m < MB; ++m) {
                    const int sp = sPrev[m];
                    float xz = (sp == 0) ? kz0 : ((sp == 1) ? kz1 : 0.f);
                    float xr = (sp == 0) ? kr0 : ((sp == 1) ? kr1 : 0.f);
                    float xh = (sp == 0) ? kn0 : ((sp == 1) ? kn1 : 0.f);
                    xz = xz + b0z;  xr = xr + b0r;  xh = xh + b0n;
                    const float hz = pacc[m][t]       + b1z;
                    const float hr = pacc[m][t + 256] + b1r;
                    const float hn = pacc[m][t + 512] + b1n;
                    const float z = 1.0f / (1.0f + expf(-(xz + hz)));
                    const float r = 1.0f / (1.0f + expf(-(xr + hr)));
                    const float rhn = r * hn;
                    const float hh = tanhf(xh + rhn);
                    hnew[m] = z * hold4[m] + (1.0f - z) * hh;
                }
            }
            hold = make_float4(hnew[0], hnew[1], hnew[2], hnew[3]);
            ((float4*)(hbase + ((n + 1) & 1) * 1024))[t] = hold;   // h_{n+1} -> other slot

            // dense logits partial reduction (h @ dense_w), waves 0..3
#pragma unroll
            for (int m = 0; m < MB; ++m) {
                float va = hnew[m] * dwa;
                float vb = hnew[m] * dwb;
#pragma unroll
                for (int off = 32; off > 0; off >>= 1) {
                    va += __shfl_xor(va, off, 64);
                    vb += __shfl_xor(vb, off, 64);
                }
                if (lane == 0) { wred[wv][2 * m] = va; wred[wv][2 * m + 1] = vb; }
            }
        }
        __syncthreads();   // B2: wred published; h store drained to L2

        // ---- phase D: 4 threads; overlaps next step's phase A (no barrier) ----
        if (t < MB) {
            const int m = t;
            float l0 = wred[0][2 * m] + wred[1][2 * m] + wred[2][2 * m] + wred[3][2 * m];
            float l1 = wred[0][2 * m + 1] + wred[1][2 * m + 1] + wred[2][2 * m + 1] + wred[3][2 * m + 1];
            uint32_t o0a, o1a, o0b, o1b;
            const uint32_t fbase = 2u * (uint32_t)(b0 + m);
            threefry(keyA[n], keyB[n], 0u, fbase,      o0a, o1a);
            threefry(keyA[n], keyB[n], 0u, fbase + 1u, o0b, o1b);
            const float g0 = gumbel_from_bits(o0a ^ o1a);
            const float g1 = gumbel_from_bits(o0b ^ o1b);
            {
#pragma clang fp contract(off)
                l0 = l0 + dba;
                l1 = l1 + dbb;
                const float mx = fmaxf(l0, l1);
                const float e0 = expf(l0 - mx), e1 = expf(l1 - mx);
                const float den = e0 + e1;
                const float lp0 = logf(1e-10f + e0 / den);
                const float lp1 = logf(1e-10f + e1 / den);
                const float v0 = g0 + lp0;
                const float v1 = g1 + lp1;
                const int s = (v1 > v0) ? 1 : 0;   // argmax, first-index tie-break
                sPrev[m] = s;
                lgP[m] = lgP[m] + (s ? lp1 : lp0);
                out[(size_t)(b0 + m) * N_SITES + n] = (float)s;
            }
        }
        // no trailing barrier: next A reads the h slot written before B2; pacc
        // WAR-safe (B's reads done before B2); sPrev consumed after next B1.
    }

    __syncthreads();
    if (t < MB) out[(size_t)NSAMP * N_SITES + (b0 + t)] = lgP[t];
}

extern "C" void kernel_launch(void* const* d_in, const int* in_sizes, int n_in,
                              void* d_out, int out_size, void* d_ws, size_t ws_size,
                              hipStream_t stream) {
    (void)in_sizes; (void)n_in; (void)ws_size; (void)out_size;
    const float* kern = (const float*)d_in[0];
    const float* rec  = (const float*)d_in[1];
    const float* bias = (const float*)d_in[2];
    const float* dwp  = (const float*)d_in[3];
    const float* dbp  = (const float*)d_in[4];
    float* out = (float*)d_out;
    float* hws = (float*)d_ws;   // needs 256 blocks * 8 KB = 2 MB of d_ws
    rnn_sample_kernel<<<NSAMP / MB, TPB, 0, stream>>>(kern, rec, bias, dwp, dbp, out, hws);
}